// Round 6
// baseline (113.696 us; speedup 1.0000x reference)
//
#include <hip/hip_runtime.h>

#define NTHREADS 256
#define N_FEAT   8192
#define EPT      32                   // elements per thread
#define NB0      2048                 // 11-bit first digit
#define SKSZ     (NB0 + NB0 / 8)      // skewed: phys(b) = b + (b>>3), 2304
#define CAP      1024                 // candidate buffer capacity

typedef float f4v __attribute__((ext_vector_type(4)));

// float -> order-preserving unsigned key (exact bijection)
__device__ __forceinline__ unsigned f2k(float f) {
    unsigned u = __float_as_uint(f);
    return u ^ (unsigned)(((int)u >> 31) | 0x80000000);
}
__device__ __forceinline__ float k2f(unsigned kk) {
    return __uint_as_float(kk ^ (unsigned)(((int)(~kk) >> 31) | 0x80000000));
}

__global__ __launch_bounds__(NTHREADS, 8) void ksparse_kernel(
    const float* __restrict__ x, const int* __restrict__ kptr,
    float* __restrict__ out) {

    const int t    = threadIdx.x;
    const int lane = t & 63;
    const int w    = t >> 6;                        // 4 waves
    const size_t base = (size_t)blockIdx.x * N_FEAT;

    __shared__ unsigned hist[SKSZ];
    __shared__ unsigned cand[CAP];
    __shared__ unsigned ws[4];
    __shared__ unsigned s_bucket, s_r, s_cnt, s_kth;

    // issue row loads; histogram clear overlaps their latency
    const f4v* xv = (const f4v*)(x + base);
    f4v c[8];
#pragma unroll
    for (int i = 0; i < 8; ++i) c[i] = xv[t + i * NTHREADS];

#pragma unroll
    for (int i = 0; i < SKSZ / NTHREADS; ++i) hist[t + i * NTHREADS] = 0u;
    if (t == 0) s_cnt = 0u;
    __syncthreads();                                 // B1

    const unsigned r = (unsigned)kptr[0] + 1u;       // (k+1)-th largest

    // ---- 11-bit histogram (skewed: adjacent buckets -> adjacent banks) ----
#pragma unroll
    for (int i = 0; i < 8; ++i)
#pragma unroll
        for (int j = 0; j < 4; ++j) {
            unsigned b = f2k(c[i][j]) >> 21;
            atomicAdd(&hist[b + (b >> 3)], 1u);
        }
    __syncthreads();                                 // B2

    // ---- all-thread suffix scan: thread t owns buckets [8t, 8t+8) ----
    // phys(8t+j) = 9t + j  (lane stride 9, gcd(9,32)=1 -> conflict-free)
    unsigned h[8], sum8 = 0;
#pragma unroll
    for (int j = 0; j < 8; ++j) { h[j] = hist[9 * t + j]; sum8 += h[j]; }
    unsigned S = sum8;
#pragma unroll
    for (int off = 1; off < 64; off <<= 1) {
        unsigned q = (unsigned)__shfl_down((int)S, off, 64);
        if (lane + off < 64) S += q;
    }
    if (lane == 0) ws[w] = S;
    __syncthreads();                                 // B3
    unsigned above = S - sum8;                       // strictly above my chunk
#pragma unroll
    for (int w2 = 1; w2 < 4; ++w2) if (w2 > w) above += ws[w2];
    if (above < r && above + sum8 >= r) {            // exactly one thread
        unsigned acc = above;
#pragma unroll
        for (int j = 7; j >= 0; --j) {
            if (acc < r && acc + h[j] >= r) { s_bucket = (unsigned)(8 * t + j); s_r = r - acc; }
            acc += h[j];
        }
    }
    __syncthreads();                                 // B4
    const unsigned bucket = s_bucket;
    const unsigned r2 = s_r;

    // ---- gather the bucket's candidates (typ. ~250 of 8192) ----
#pragma unroll
    for (int i = 0; i < 8; ++i)
#pragma unroll
        for (int j = 0; j < 4; ++j) {
            unsigned kk = f2k(c[i][j]);
            if ((kk >> 21) == bucket) {
                unsigned q = atomicAdd(&s_cnt, 1u);
                if (q < CAP) cand[q] = kk;
            }
        }
    __syncthreads();                                 // B5
    const unsigned m = s_cnt;

    if (m <= CAP) {
        // exact rank via pairwise count (cand[j2] reads broadcast, conflict-free)
        for (unsigned i = t; i < m; i += NTHREADS) {
            unsigned ki = cand[i], g = 0, ge = 0;
            for (unsigned j2 = 0; j2 < m; ++j2) {
                unsigned kj = cand[j2];
                g  += (kj > ki);
                ge += (kj >= ki);
            }
            if (g < r2 && ge >= r2) s_kth = ki;      // unique value, race-safe
        }
    } else {
        // adversarial-only fallback: finish remaining 21 bits with 2 radix passes
        // (11 bits then 10 bits), serial wave-0 scan — never taken on this data.
        unsigned prefix = bucket << 21, rk = r2;
#pragma unroll
        for (int pass = 0; pass < 2; ++pass) {
            const int shift = pass == 0 ? 10 : 0;
            const int nb    = pass == 0 ? 2048 : 1024;
            const unsigned hm = pass == 0 ? 0xFFE00000u : 0xFFFFFC00u;
            for (int i = 0; i < SKSZ / NTHREADS; ++i) hist[t + i * NTHREADS] = 0u;
            __syncthreads();
            for (int i = 0; i < 8; ++i)
                for (int j = 0; j < 4; ++j) {
                    unsigned kk = f2k(c[i][j]);
                    if ((kk & hm) == prefix)
                        atomicAdd(&hist[(kk >> shift) & (nb - 1)], 1u);
                }
            __syncthreads();
            if (t < 64) {
                const int per = nb / 64;
                unsigned C = 0;
                for (int j2 = 0; j2 < per; ++j2) C += hist[t * per + j2];
                unsigned S2 = C;
                for (int off = 1; off < 64; off <<= 1) {
                    unsigned q = (unsigned)__shfl_down((int)S2, off, 64);
                    if (lane + off < 64) S2 += q;
                }
                unsigned carry = S2 - C;
                if (S2 >= rk && carry < rk) {
                    unsigned acc = carry;
                    for (int j2 = per - 1; j2 >= 0; --j2) {
                        unsigned hj = hist[t * per + j2];
                        if (acc < rk && acc + hj >= rk) { s_bucket = (unsigned)(t * per + j2); s_r = rk - acc; }
                        acc += hj;
                    }
                }
            }
            __syncthreads();
            prefix |= s_bucket << shift;
            rk = s_r;
        }
        if (t == 0) s_kth = prefix;
    }
    __syncthreads();                                 // B6
    const float kthf = k2f(s_kth);

    // ---- masked write: float compare == reference semantics exactly ----
    f4v* ov = (f4v*)(out + base);
#pragma unroll
    for (int i = 0; i < 8; ++i) {
        f4v o;
#pragma unroll
        for (int j = 0; j < 4; ++j) o[j] = (c[i][j] > kthf) ? c[i][j] : 0.0f;
        __builtin_nontemporal_store(o, ov + t + i * NTHREADS);
    }
}

extern "C" void kernel_launch(void* const* d_in, const int* in_sizes, int n_in,
                              void* d_out, int out_size, void* d_ws, size_t ws_size,
                              hipStream_t stream) {
    const float* x = (const float*)d_in[0];
    const int* k   = (const int*)d_in[1];
    float* out     = (float*)d_out;
    const int B = in_sizes[0] / N_FEAT;
    ksparse_kernel<<<B, NTHREADS, 0, stream>>>(x, k, out);
}

// Round 7
// 90.518 us; speedup vs baseline: 1.2561x; 1.2561x over previous
//
#include <hip/hip_runtime.h>

#define NTHREADS 256
#define N_FEAT   8192
#define NB0      2048                 // 11-bit first digit
#define SKSZ     (NB0 + NB0 / 8)      // skewed: phys(b) = b + (b>>3), 2304
#define CAP      1024                 // candidate buffer capacity

typedef float f4v __attribute__((ext_vector_type(4)));

// float -> order-preserving unsigned key (exact bijection)
__device__ __forceinline__ unsigned f2k(float f) {
    unsigned u = __float_as_uint(f);
    return u ^ (unsigned)(((int)u >> 31) | 0x80000000);
}
__device__ __forceinline__ float k2f(unsigned kk) {
    return __uint_as_float(kk ^ (unsigned)(((int)(~kk) >> 31) | 0x80000000));
}

// Row data is NOT kept in registers: each phase re-reads the row from global
// (L1/L2-resident after the first pass). Keeps VGPR ~40 -> 8 blocks/CU of
// independent phase-streams; spills (R6's 2.4x traffic inflation) impossible.
__global__ __launch_bounds__(NTHREADS, 8) void ksparse_kernel(
    const float* __restrict__ x, const int* __restrict__ kptr,
    float* __restrict__ out) {

    const int t    = threadIdx.x;
    const int lane = t & 63;
    const int w    = t >> 6;                        // 4 waves
    const size_t base = (size_t)blockIdx.x * N_FEAT;

    __shared__ unsigned hist[SKSZ];
    __shared__ unsigned cand[CAP];
    __shared__ unsigned ws[4];
    __shared__ unsigned s_bucket, s_r, s_cnt, s_kth;

    const f4v* xv = (const f4v*)(x + base);

#pragma unroll
    for (int i = 0; i < SKSZ / NTHREADS; ++i) hist[t + i * NTHREADS] = 0u;
    if (t == 0) s_cnt = 0u;
    __syncthreads();                                 // B1

    const unsigned r = (unsigned)kptr[0] + 1u;       // (k+1)-th largest

    // ---- pass 1: 11-bit histogram (transient loads, skewed buckets) ----
#pragma unroll
    for (int i = 0; i < 8; ++i) {
        f4v v = xv[t + i * NTHREADS];
#pragma unroll
        for (int j = 0; j < 4; ++j) {
            unsigned b = f2k(v[j]) >> 21;
            atomicAdd(&hist[b + (b >> 3)], 1u);
        }
    }
    __syncthreads();                                 // B2

    // ---- all-thread suffix scan: thread t owns buckets [8t, 8t+8) ----
    // phys(8t+j) = 9t + j  (lane stride 9, gcd(9,32)=1 -> conflict-free)
    unsigned h[8], sum8 = 0;
#pragma unroll
    for (int j = 0; j < 8; ++j) { h[j] = hist[9 * t + j]; sum8 += h[j]; }
    unsigned S = sum8;
#pragma unroll
    for (int off = 1; off < 64; off <<= 1) {
        unsigned q = (unsigned)__shfl_down((int)S, off, 64);
        if (lane + off < 64) S += q;
    }
    if (lane == 0) ws[w] = S;
    __syncthreads();                                 // B3
    unsigned above = S - sum8;                       // strictly above my chunk
#pragma unroll
    for (int w2 = 1; w2 < 4; ++w2) if (w2 > w) above += ws[w2];
    if (above < r && above + sum8 >= r) {            // exactly one thread
        unsigned acc = above;
#pragma unroll
        for (int j = 7; j >= 0; --j) {
            if (acc < r && acc + h[j] >= r) { s_bucket = (unsigned)(8 * t + j); s_r = r - acc; }
            acc += h[j];
        }
    }
    __syncthreads();                                 // B4
    const unsigned bucket = s_bucket;
    const unsigned r2 = s_r;

    // ---- pass 2: gather the bucket's candidates (typ. ~250; L2 re-read) ----
#pragma unroll
    for (int i = 0; i < 8; ++i) {
        f4v v = xv[t + i * NTHREADS];
#pragma unroll
        for (int j = 0; j < 4; ++j) {
            unsigned kk = f2k(v[j]);
            if ((kk >> 21) == bucket) {
                unsigned q = atomicAdd(&s_cnt, 1u);
                if (q < CAP) cand[q] = kk;
            }
        }
    }
    __syncthreads();                                 // B5
    const unsigned m = s_cnt;

    if (m <= CAP) {
        // exact rank via pairwise count (cand[j2] reads broadcast, conflict-free)
        for (unsigned i = t; i < m; i += NTHREADS) {
            unsigned ki = cand[i], g = 0, ge = 0;
            for (unsigned j2 = 0; j2 < m; ++j2) {
                unsigned kj = cand[j2];
                g  += (kj > ki);
                ge += (kj >= ki);
            }
            if (g < r2 && ge >= r2) s_kth = ki;      // unique value, race-safe
        }
    } else {
        // adversarial-only fallback: finish remaining 21 bits (11 then 10),
        // re-reading the row per pass. Never taken on this data.
        unsigned prefix = bucket << 21, rk = r2;
        for (int pass = 0; pass < 2; ++pass) {
            const int shift = pass == 0 ? 10 : 0;
            const int nb    = pass == 0 ? 2048 : 1024;
            const unsigned hm = pass == 0 ? 0xFFE00000u : 0xFFFFFC00u;
            for (int i = 0; i < SKSZ / NTHREADS; ++i) hist[t + i * NTHREADS] = 0u;
            __syncthreads();
            for (int i = 0; i < 8; ++i) {
                f4v v = xv[t + i * NTHREADS];
                for (int j = 0; j < 4; ++j) {
                    unsigned kk = f2k(v[j]);
                    if ((kk & hm) == prefix)
                        atomicAdd(&hist[(kk >> shift) & (nb - 1)], 1u);
                }
            }
            __syncthreads();
            if (t < 64) {
                const int per = nb / 64;
                unsigned C = 0;
                for (int j2 = 0; j2 < per; ++j2) C += hist[t * per + j2];
                unsigned S2 = C;
                for (int off = 1; off < 64; off <<= 1) {
                    unsigned q = (unsigned)__shfl_down((int)S2, off, 64);
                    if (lane + off < 64) S2 += q;
                }
                unsigned carry = S2 - C;
                if (S2 >= rk && carry < rk) {
                    unsigned acc = carry;
                    for (int j2 = per - 1; j2 >= 0; --j2) {
                        unsigned hj = hist[t * per + j2];
                        if (acc < rk && acc + hj >= rk) { s_bucket = (unsigned)(t * per + j2); s_r = rk - acc; }
                        acc += hj;
                    }
                }
            }
            __syncthreads();
            prefix |= s_bucket << shift;
            rk = s_r;
        }
        if (t == 0) s_kth = prefix;
    }
    __syncthreads();                                 // B6
    const float kthf = k2f(s_kth);

    // ---- pass 3: masked write (L2 re-read; float compare == ref exactly) ----
    f4v* ov = (f4v*)(out + base);
#pragma unroll
    for (int i = 0; i < 8; ++i) {
        f4v v = xv[t + i * NTHREADS];
        f4v o;
#pragma unroll
        for (int j = 0; j < 4; ++j) o[j] = (v[j] > kthf) ? v[j] : 0.0f;
        __builtin_nontemporal_store(o, ov + t + i * NTHREADS);
    }
}

extern "C" void kernel_launch(void* const* d_in, const int* in_sizes, int n_in,
                              void* d_out, int out_size, void* d_ws, size_t ws_size,
                              hipStream_t stream) {
    const float* x = (const float*)d_in[0];
    const int* k   = (const int*)d_in[1];
    float* out     = (float*)d_out;
    const int B = in_sizes[0] / N_FEAT;
    ksparse_kernel<<<B, NTHREADS, 0, stream>>>(x, k, out);
}

// Round 8
// 66.305 us; speedup vs baseline: 1.7147x; 1.3652x over previous
//
#include <hip/hip_runtime.h>

#define NTHREADS 512
#define N_FEAT   8192
#define NB0      8192                 // 13-bit first digit
#define SKSZ     (NB0 + NB0 / 16)     // skewed: phys(b) = b + (b>>4), 8704 = 17*512
#define CAP      512                  // candidate buffer capacity

typedef float f4v __attribute__((ext_vector_type(4)));

// float -> order-preserving unsigned key (exact bijection)
__device__ __forceinline__ unsigned f2k(float f) {
    unsigned u = __float_as_uint(f);
    return u ^ (unsigned)(((int)u >> 31) | 0x80000000);
}
__device__ __forceinline__ float k2f(unsigned kk) {
    return __uint_as_float(kk ^ (unsigned)(((int)(~kk) >> 31) | 0x80000000));
}

__global__ __launch_bounds__(NTHREADS) void ksparse_kernel(
    const float* __restrict__ x, const int* __restrict__ kptr,
    float* __restrict__ out) {

    const int t    = threadIdx.x;
    const int lane = t & 63;
    const int w    = t >> 6;                        // 8 waves
    const size_t base = (size_t)blockIdx.x * N_FEAT;

    __shared__ unsigned hist[SKSZ];
    __shared__ unsigned cand[CAP];
    __shared__ unsigned ws[8];
    __shared__ unsigned s_bucket, s_r, s_cnt, s_kth;

    // issue row loads first: their latency overlaps the stagger-sleep + clear
    const f4v* xv = (const f4v*)(x + base);
    f4v c0 = xv[t], c1 = xv[t + 512], c2 = xv[t + 1024], c3 = xv[t + 1536];

    // ---- anti-lockstep stagger (first generation of resident blocks only) ----
    // Co-resident blocks start in phase and run identical-length work, so their
    // select phases collide forever (memory idles ~23% of the time). Offset the
    // first generation by stage*2.7us; refills inherit the stagger.
    if (blockIdx.x < 1024) {
        int stage = (blockIdx.x ^ (blockIdx.x >> 8)) & 3;
        for (int i = 0; i < stage; ++i)
            __builtin_amdgcn_s_sleep(100);          // ~6400 cy = 2.7us each
    }

#pragma unroll
    for (int i = 0; i < SKSZ / NTHREADS; ++i) hist[t + i * NTHREADS] = 0u;
    if (t == 0) s_cnt = 0u;
    __syncthreads();                                 // B1

    const unsigned r = (unsigned)kptr[0] + 1u;       // (k+1)-th largest

    // ---- 13-bit histogram (skewed: adjacent buckets -> adjacent banks) ----
    {
        auto h4 = [&](f4v v) {
#pragma unroll
            for (int j = 0; j < 4; ++j) {
                unsigned b = f2k(v[j]) >> 19;
                atomicAdd(&hist[b + (b >> 4)], 1u);
            }
        };
        h4(c0); h4(c1); h4(c2); h4(c3);
    }
    __syncthreads();                                 // B2

    // ---- all-thread suffix scan: thread t owns buckets [16t, 16t+16) ----
    // phys(16t+j) = 17t + j  (lane stride 17, gcd(17,32)=1 -> conflict-free)
    unsigned h[16], sum16 = 0;
#pragma unroll
    for (int j = 0; j < 16; ++j) { h[j] = hist[17 * t + j]; sum16 += h[j]; }
    unsigned S = sum16;
#pragma unroll
    for (int off = 1; off < 64; off <<= 1) {
        unsigned q = (unsigned)__shfl_down((int)S, off, 64);
        if (lane + off < 64) S += q;
    }
    if (lane == 0) ws[w] = S;
    __syncthreads();                                 // B3
    unsigned above = S - sum16;                      // strictly above my chunk
#pragma unroll
    for (int w2 = 1; w2 < 8; ++w2) if (w2 > w) above += ws[w2];
    if (above < r && above + sum16 >= r) {           // exactly one thread
        unsigned acc = above;
#pragma unroll
        for (int j = 15; j >= 0; --j) {
            if (acc < r && acc + h[j] >= r) { s_bucket = (unsigned)(16 * t + j); s_r = r - acc; }
            acc += h[j];
        }
    }
    __syncthreads();                                 // B4
    const unsigned bucket = s_bucket;
    const unsigned r2 = s_r;

    // ---- gather the bucket's candidates (typ. ~65 of 8192) ----
    {
        auto g4 = [&](f4v v) {
#pragma unroll
            for (int j = 0; j < 4; ++j) {
                unsigned kk = f2k(v[j]);
                if ((kk >> 19) == bucket) {
                    unsigned q = atomicAdd(&s_cnt, 1u);
                    if (q < CAP) cand[q] = kk;
                }
            }
        };
        g4(c0); g4(c1); g4(c2); g4(c3);
    }
    __syncthreads();                                 // B5
    const unsigned m = s_cnt;

    if (m <= CAP) {
        // exact rank via pairwise count (cand[j2] reads broadcast, conflict-free)
        for (unsigned i = t; i < m; i += NTHREADS) {
            unsigned ki = cand[i], g = 0, ge = 0;
            for (unsigned j2 = 0; j2 < m; ++j2) {
                unsigned kj = cand[j2];
                g  += (kj > ki);
                ge += (kj >= ki);
            }
            if (g < r2 && ge >= r2) s_kth = ki;      // unique value, race-safe
        }
    } else {
        // adversarial-only fallback: finish remaining 19 bits (10 then 9),
        // serial wave-0 scan. Never taken on N(0,1) data.
        unsigned prefix = bucket << 19, rk = r2;
        for (int pass = 0; pass < 2; ++pass) {
            const int shift = pass == 0 ? 9 : 0;
            const int nb    = pass == 0 ? 1024 : 512;
            const unsigned hm = pass == 0 ? 0xFFF80000u : 0xFFFFFE00u;
            hist[t] = 0u; hist[t + 512] = 0u;
            __syncthreads();
            auto a4 = [&](f4v v) {
#pragma unroll
                for (int j = 0; j < 4; ++j) {
                    unsigned kk = f2k(v[j]);
                    if ((kk & hm) == prefix) atomicAdd(&hist[(kk >> shift) & (nb - 1)], 1u);
                }
            };
            a4(c0); a4(c1); a4(c2); a4(c3);
            __syncthreads();
            if (t < 64) {
                const int per = nb / 64;
                unsigned C = 0;
                for (int j2 = 0; j2 < per; ++j2) C += hist[t * per + j2];
                unsigned S2 = C;
                for (int off = 1; off < 64; off <<= 1) {
                    unsigned q = (unsigned)__shfl_down((int)S2, off, 64);
                    if (lane + off < 64) S2 += q;
                }
                unsigned carry = S2 - C;
                if (S2 >= rk && carry < rk) {
                    unsigned acc = carry;
                    for (int j2 = per - 1; j2 >= 0; --j2) {
                        unsigned hj = hist[t * per + j2];
                        if (acc < rk && acc + hj >= rk) { s_bucket = (unsigned)(t * per + j2); s_r = rk - acc; }
                        acc += hj;
                    }
                }
            }
            __syncthreads();
            prefix |= s_bucket << shift;
            rk = s_r;
        }
        if (t == 0) s_kth = prefix;
    }
    __syncthreads();                                 // B6
    const float kthf = k2f(s_kth);

    // ---- masked write: float compare == reference semantics exactly ----
    f4v* ov = (f4v*)(out + base);
    {
        auto w4 = [&](f4v v, int idx) {
            f4v o;
#pragma unroll
            for (int j = 0; j < 4; ++j) o[j] = (v[j] > kthf) ? v[j] : 0.0f;
            __builtin_nontemporal_store(o, ov + idx);
        };
        w4(c0, t); w4(c1, t + 512); w4(c2, t + 1024); w4(c3, t + 1536);
    }
}

extern "C" void kernel_launch(void* const* d_in, const int* in_sizes, int n_in,
                              void* d_out, int out_size, void* d_ws, size_t ws_size,
                              hipStream_t stream) {
    const float* x = (const float*)d_in[0];
    const int* k   = (const int*)d_in[1];
    float* out     = (float*)d_out;
    const int B = in_sizes[0] / N_FEAT;
    ksparse_kernel<<<B, NTHREADS, 0, stream>>>(x, k, out);
}

// Round 9
// 55.770 us; speedup vs baseline: 2.0387x; 1.1889x over previous
//
#include <hip/hip_runtime.h>

#define NTHREADS 512
#define GT       256                  // threads per group; one row per group
#define NGRP     (NTHREADS / GT)      // 2 rows per block
#define N_FEAT   8192
#define VPT      8                    // f4v loads per thread (32 elems)
#define NB1      2048                 // 11-bit digit
#define SKSZ     (NB1 + NB1 / 8)      // 2304 words per group (skew holes)
#define SK(b)    ((b) + ((b) >> 3))   // injective; scan lane-stride 9 (gcd(9,32)=1)

typedef float f4v __attribute__((ext_vector_type(4)));

// float -> order-preserving unsigned key (exact bijection)
__device__ __forceinline__ unsigned f2k(float f) {
    unsigned u = __float_as_uint(f);
    return u ^ (unsigned)(((int)u >> 31) | 0x80000000);
}
__device__ __forceinline__ float k2f(unsigned kk) {
    return __uint_as_float(kk ^ (unsigned)(((int)(~kk) >> 31) | 0x80000000));
}

// One radix level: read per-thread buckets (and re-clear them for the next
// level), suffix-scan across the group (intra-wave shuffle + 4-wave combine),
// locate the bucket containing rank r (counted from the top).
template<int PER>
__device__ __forceinline__ void scan_locate(unsigned* __restrict__ histg,
                                            volatile unsigned* wsg,
                                            unsigned* s_bucket, unsigned* s_r,
                                            unsigned r, int tg, int lane, int wg) {
    unsigned h[PER], sum = 0;
#pragma unroll
    for (int j = 0; j < PER; ++j) {
        const int b = PER * tg + j;
        h[j] = histg[SK(b)];
        histg[SK(b)] = 0u;                       // fused re-clear for next level
        sum += h[j];
    }
    unsigned S = sum;                            // wave inclusive suffix scan
#pragma unroll
    for (int off = 1; off < 64; off <<= 1) {
        unsigned q = (unsigned)__shfl_down((int)S, off, 64);
        if (lane + off < 64) S += q;
    }
    if (lane == 0) wsg[wg] = S;
    __syncthreads();
    unsigned above = S - sum;                    // strictly above my buckets
#pragma unroll
    for (int w2 = 1; w2 < GT / 64; ++w2) if (w2 > wg) above += wsg[w2];
    if (above < r && above + sum >= r) {         // exactly one thread straddles
        unsigned acc = above;
#pragma unroll
        for (int j = PER - 1; j >= 0; --j) {
            if (acc < r && acc + h[j] >= r) { *s_bucket = (unsigned)(PER * tg + j); *s_r = r - acc; }
            acc += h[j];
        }
    }
    __syncthreads();
}

__global__ __launch_bounds__(NTHREADS) void ksparse_kernel(
    const float* __restrict__ x, const int* __restrict__ kptr,
    float* __restrict__ out, int nrows) {

    const int t    = threadIdx.x;
    const int g    = t >> 8;                    // group (row) within block
    const int tg   = t & (GT - 1);
    const int lane = t & 63;
    const int wg   = (t >> 6) & 3;              // wave within group

    __shared__ unsigned hist[NGRP][SKSZ];
    __shared__ unsigned ws[NGRP][GT / 64];
    __shared__ unsigned s_bucket[NGRP], s_r[NGRP];

    const int rowid = blockIdx.x * NGRP + g;
    const bool valid = rowid < nrows;
    const size_t base = (size_t)(valid ? rowid : 0) * N_FEAT;
    const f4v* xv = (const f4v*)(x + base);

    // issue row loads first; clear overlaps their latency
    f4v v[VPT];
#pragma unroll
    for (int i = 0; i < VPT; ++i) v[i] = xv[tg + i * GT];

#pragma unroll
    for (int i = 0; i < (NGRP * SKSZ) / NTHREADS; ++i)
        (&hist[0][0])[t + i * NTHREADS] = 0u;
    __syncthreads();                             // B1

    unsigned key[VPT][4];
#pragma unroll
    for (int i = 0; i < VPT; ++i)
#pragma unroll
        for (int j = 0; j < 4; ++j) key[i][j] = f2k(v[i][j]);

    unsigned r = (unsigned)kptr[0] + 1u;         // (k+1)-th largest
    unsigned* histg = hist[g];

    // ---- pass 1: bits 31..21 ----
#pragma unroll
    for (int i = 0; i < VPT; ++i)
#pragma unroll
        for (int j = 0; j < 4; ++j)
            atomicAdd(&histg[SK(key[i][j] >> 21)], 1u);
    __syncthreads();
    scan_locate<NB1 / GT>(histg, ws[g], &s_bucket[g], &s_r[g], r, tg, lane, wg);
    const unsigned b1 = s_bucket[g];
    r = s_r[g];

    // ---- pass 2: bits 20..10 among keys whose top-11 == b1 ----
#pragma unroll
    for (int i = 0; i < VPT; ++i)
#pragma unroll
        for (int j = 0; j < 4; ++j) {
            unsigned kk = key[i][j];
            if ((kk >> 21) == b1) atomicAdd(&histg[SK((kk >> 10) & 2047u)], 1u);
        }
    __syncthreads();
    scan_locate<NB1 / GT>(histg, ws[g], &s_bucket[g], &s_r[g], r, tg, lane, wg);
    const unsigned p22 = (b1 << 11) | s_bucket[g];
    r = s_r[g];

    // ---- pass 3: bits 9..0 among keys whose top-22 == p22 ----
#pragma unroll
    for (int i = 0; i < VPT; ++i)
#pragma unroll
        for (int j = 0; j < 4; ++j) {
            unsigned kk = key[i][j];
            if ((kk >> 10) == p22) atomicAdd(&histg[SK(kk & 1023u)], 1u);
        }
    __syncthreads();
    scan_locate<1024 / GT>(histg, ws[g], &s_bucket[g], &s_r[g], r, tg, lane, wg);
    const unsigned kth = (p22 << 10) | s_bucket[g];  // exact (k+1)-th largest key

    // ---- masked write (nontemporal; key compare == float compare, exact) ----
    if (valid) {
        f4v* ov = (f4v*)(out + base);
#pragma unroll
        for (int i = 0; i < VPT; ++i) {
            f4v o;
#pragma unroll
            for (int j = 0; j < 4; ++j) {
                unsigned kk = key[i][j];
                o[j] = (kk > kth) ? k2f(kk) : 0.0f;
            }
            __builtin_nontemporal_store(o, ov + tg + i * GT);
        }
    }
}

extern "C" void kernel_launch(void* const* d_in, const int* in_sizes, int n_in,
                              void* d_out, int out_size, void* d_ws, size_t ws_size,
                              hipStream_t stream) {
    const float* x = (const float*)d_in[0];
    const int* k   = (const int*)d_in[1];
    float* out     = (float*)d_out;
    const int B = in_sizes[0] / N_FEAT;
    const int grid = (B + NGRP - 1) / NGRP;
    ksparse_kernel<<<grid, NTHREADS, 0, stream>>>(x, k, out, B);
}